// Round 5
// baseline (126.718 us; speedup 1.0000x reference)
//
#include <hip/hip_runtime.h>
#include <math.h>

constexpr int Bn = 64, Sn = 6, Tn = 2000, Cn = 25;
constexpr int COLS = Sn * Tn;              // 12000
constexpr int ROWS = Bn * Sn * Tn;         // 768000
constexpr int BDIM = 256;
constexpr int RPB  = 256;                  // rows per fret block
constexpr int FBLK = ROWS / RPB;           // 3000 fret blocks (exact)
constexpr int FPAD = 3072;                 // padded leading dim for pf
constexpr int OBLK = (COLS + BDIM - 1) / BDIM;  // 47 onset blocks
constexpr int OPAD = 64;
constexpr int GRID = FBLK + OBLK;          // 3047

// d_ws layout: pf[Sn][FPAD] fret per-string per-block partials (72 KB, transposed
//              for coalesced finish reads), then po[Sn][OPAD] onset partials.

__global__ __launch_bounds__(BDIM) void main_kernel(const float4* __restrict__ x4,
                                                    const int*    __restrict__ tgt,
                                                    const float*  __restrict__ ox,
                                                    const float*  __restrict__ ot,
                                                    float* __restrict__ pf,
                                                    float* __restrict__ po) {
    __shared__ float lds[RPB * Cn];        // 25.6 KB row stage (fret path only)
    __shared__ float ls[Sn];
    const int tid  = threadIdx.x;
    const int lane = tid & 63;
    if (tid < Sn) ls[tid] = 0.0f;

    if (blockIdx.x < OBLK) {
        // ---------------- onset path: softmax over B per column ----------------
        __syncthreads();
        const int col = blockIdx.x * BDIM + tid;
        if (col < COLS) {
            float M = -INFINITY, S = 0.0f, ts = 0.0f, txs = 0.0f;
            for (int b0 = 0; b0 < Bn; b0 += 16) {
                float xv[16];
                #pragma unroll
                for (int k = 0; k < 16; ++k) xv[k] = ox[(b0 + k) * COLS + col];
                #pragma unroll
                for (int k = 0; k < 16; ++k) {
                    const float tv = ot[(b0 + k) * COLS + col];
                    ts  += tv;
                    txs += tv * xv[k];
                }
                float cm = -INFINITY;
                #pragma unroll
                for (int k = 0; k < 16; ++k) cm = fmaxf(cm, xv[k]);
                float cs = 0.0f;
                #pragma unroll
                for (int k = 0; k < 16; ++k) cs += __expf(xv[k] - cm);
                const float nm = fmaxf(M, cm);
                S = S * __expf(M - nm) + cs * __expf(cm - nm);   // exp(-inf)=0 first iter
                M = nm;
            }
            const float on = ts * (M + __logf(S)) - txs;
            atomicAdd(&ls[col / Tn], on);
        }
        __syncthreads();
        if (tid < Sn) po[tid * OPAD + blockIdx.x] = ls[tid];
    } else {
        // ---------------- fret path: CE over 25 classes per row ----------------
        const int fb = blockIdx.x - OBLK;
        // stage 256 rows = 1600 float4, fully coalesced
        const float4* src = x4 + (long)fb * (RPB * Cn / 4);
        float4* lds4 = (float4*)lds;
        #pragma unroll
        for (int k = tid; k < RPB * Cn / 4; k += BDIM) lds4[k] = src[k];
        __syncthreads();

        const int   row   = fb * RPB + tid;
        const float* myrow = lds + tid * Cn;        // stride 25: free 2-way aliasing
        float m = -INFINITY;
        #pragma unroll
        for (int c = 0; c < Cn; ++c) m = fmaxf(m, myrow[c]);
        float sum = 0.0f;
        #pragma unroll
        for (int c = 0; c < Cn; ++c) sum += __expf(myrow[c] - m);
        const float nll = m + __logf(sum) - myrow[tgt[row]];

        // 64 consecutive rows span at most 2 strings (Tn=2000 > 64):
        // butterfly-reduce the two groups, then <=2 LDS atomics per wave
        // (same-address ds atomics serialize -- R4 lesson).
        const int s  = (row / Tn) % Sn;
        const int s0 = __shfl(s, 0, 64);
        const int s1 = __shfl(s, 63, 64);
        float v0 = (s == s0) ? nll : 0.0f;
        float v1 = (s == s0) ? 0.0f : nll;
        #pragma unroll
        for (int off = 32; off > 0; off >>= 1) {
            v0 += __shfl_xor(v0, off, 64);
            v1 += __shfl_xor(v1, off, 64);
        }
        if (lane == 0) {
            atomicAdd(&ls[s0], v0);
            if (s1 != s0) atomicAdd(&ls[s1], v1);
        }
        __syncthreads();
        if (tid < Sn) pf[tid * FPAD + fb] = ls[tid];
    }
}

__global__ __launch_bounds__(1024) void finish_kernel(const float* __restrict__ pf,
                                                      const float* __restrict__ po,
                                                      float* __restrict__ out) {
    __shared__ float acc[2 * Sn];
    const int tid  = threadIdx.x;
    const int lane = tid & 63;
    if (tid < 2 * Sn) acc[tid] = 0.0f;
    __syncthreads();

    // ---- fret partials: 6 coalesced strided sweeps, wave-butterfly reduce ----
    float fs[Sn];
    #pragma unroll
    for (int s = 0; s < Sn; ++s) {
        float v = 0.0f;
        for (int i = tid; i < FBLK; i += 1024) v += pf[s * FPAD + i];  // coalesced
        fs[s] = v;
    }
    #pragma unroll
    for (int off = 32; off > 0; off >>= 1) {
        #pragma unroll
        for (int s = 0; s < Sn; ++s) fs[s] += __shfl_xor(fs[s], off, 64);
    }
    if (lane == 0) {
        #pragma unroll
        for (int s = 0; s < Sn; ++s) atomicAdd(&acc[s], fs[s]);   // 16 waves x 6
    }

    // ---- onset partials: wave w sums string w (47 entries) ----
    const int w = tid >> 6;
    if (w < Sn) {
        float v = (lane < OBLK) ? po[w * OPAD + lane] : 0.0f;
        #pragma unroll
        for (int off = 32; off > 0; off >>= 1) v += __shfl_xor(v, off, 64);
        if (lane == 0) acc[Sn + w] = v;
    }
    __syncthreads();

    if (tid == 0) {
        float fret = 0.0f, on = 0.0f, fsv[Sn], osv[Sn];
        #pragma unroll
        for (int s = 0; s < Sn; ++s) {
            fsv[s] = acc[s] * (1.0f / Bn);          // mean over batch
            osv[s] = acc[Sn + s];
            fret += fsv[s];
            on   += osv[s];
        }
        out[0] = 0.5f * fret + 0.5f * on;           // WEIGHT_FRET_ONSET = 0.5
        out[1] = fret;
        out[2] = on;
        #pragma unroll
        for (int s = 0; s < Sn; ++s) { out[3 + s] = fsv[s]; out[9 + s] = osv[s]; }
    }
}

extern "C" void kernel_launch(void* const* d_in, const int* in_sizes, int n_in,
                              void* d_out, int out_size, void* d_ws, size_t ws_size,
                              hipStream_t stream) {
    const float* output_fret  = (const float*)d_in[0];
    const int*   target_fret  = (const int*)d_in[1];
    const float* output_onset = (const float*)d_in[2];
    const float* target_onset = (const float*)d_in[3];
    float* pf  = (float*)d_ws;                 // [Sn][FPAD]
    float* po  = pf + Sn * FPAD;               // [Sn][OPAD]
    float* out = (float*)d_out;

    main_kernel<<<GRID, BDIM, 0, stream>>>((const float4*)output_fret, target_fret,
                                           output_onset, target_onset, pf, po);
    finish_kernel<<<1, 1024, 0, stream>>>(pf, po, out);
}